// Round 2
// baseline (486.679 us; speedup 1.0000x reference)
//
#include <hip/hip_runtime.h>

#define NB 8
#define NT 2048
#define NC 2048
#define NH 128

typedef short s8v __attribute__((ext_vector_type(8)));   // 8 bf16 (4 VGPRs) — MFMA A/B frag
typedef float f4  __attribute__((ext_vector_type(4)));   // 4 fp32 — MFMA C/D frag

static __device__ __forceinline__ unsigned short f2bf(float f) {
    union { float f; unsigned int u; } v; v.f = f;
    unsigned int x = v.u;
    return (unsigned short)((x + 0x7FFFu + ((x >> 16) & 1u)) >> 16);  // RNE
}

// ---------------------------------------------------------------------------
// Kernel 0: transpose + cast W[k][n] (2048x128 fp32) -> Wt[n][k] (128x2048 bf16)
// for Q,K,V. Makes the GEMM B-fragment (lane holds col n=lane&15, k=quad*8+j
// contiguous) a single 16B load. wt layout: mat*262144 + n*2048 + k; 0=Q,1=K,2=V.
// ---------------------------------------------------------------------------
__global__ __launch_bounds__(256) void wtrans_k(
    const float* __restrict__ Wk, const float* __restrict__ Wq,
    const float* __restrict__ Wv, unsigned short* __restrict__ wt)
{
    int tid = blockIdx.x * 256 + threadIdx.x;          // 0 .. 786431
    int mat = tid >> 18;                               // /262144
    int r   = tid & 0x3FFFF;
    int n   = r >> 11;                                 // /2048
    int k   = r & 2047;
    const float* W = (mat == 0) ? Wq : (mat == 1) ? Wk : Wv;
    wt[tid] = f2bf(W[k * NH + n]);
}

// ---------------------------------------------------------------------------
// Kernel 1: fused projection + RoPE.  x is fp32; converted to bf16 in-register.
// grid = (128 row-tiles of 128, 3 matrices), block = 256 (4 waves).
// Each wave: 32 rows x 128 cols, K-loop 2048 in steps of 32 (16 MFMAs/step).
// Epilogue: RoPE for Q/K via shfl_xor(1) even/odd pairing; V stored transposed
// Vt[b][d][t] (bf16) so attention's PV B-operand is contiguous in t.
// ---------------------------------------------------------------------------
__global__ __launch_bounds__(256) void proj_rope(
    const float* __restrict__ x, const unsigned short* __restrict__ wt,
    unsigned short* __restrict__ qws, unsigned short* __restrict__ kws,
    unsigned short* __restrict__ vtws)
{
    const int mat  = blockIdx.y;               // 0=Q 1=K 2=V
    const int wave = threadIdx.x >> 6;
    const int lane = threadIdx.x & 63;
    const int quad = lane >> 4, l16 = lane & 15;
    const int row0 = blockIdx.x * 128 + wave * 32;
    const unsigned short* wtm = wt + mat * (NH * NC);

    f4 acc[2][8];
    #pragma unroll
    for (int mi = 0; mi < 2; ++mi)
        #pragma unroll
        for (int ni = 0; ni < 8; ++ni)
            acc[mi][ni] = (f4){0.f, 0.f, 0.f, 0.f};

    for (int kk = 0; kk < NC; kk += 32) {
        s8v a[2];
        #pragma unroll
        for (int mi = 0; mi < 2; ++mi) {
            const float* xr = x + (size_t)(row0 + mi * 16 + l16) * NC + kk + quad * 8;
            f4 x0 = *reinterpret_cast<const f4*>(xr);
            f4 x1 = *reinterpret_cast<const f4*>(xr + 4);
            s8v av;
            #pragma unroll
            for (int j = 0; j < 4; ++j) {
                av[j]     = (short)f2bf(x0[j]);
                av[j + 4] = (short)f2bf(x1[j]);
            }
            a[mi] = av;
        }
        #pragma unroll
        for (int ni = 0; ni < 8; ++ni) {
            s8v b = *reinterpret_cast<const s8v*>(
                wtm + (size_t)(ni * 16 + l16) * NC + kk + quad * 8);
            acc[0][ni] = __builtin_amdgcn_mfma_f32_16x16x32_bf16(a[0], b, acc[0][ni], 0, 0, 0);
            acc[1][ni] = __builtin_amdgcn_mfma_f32_16x16x32_bf16(a[1], b, acc[1][ni], 0, 0, 0);
        }
    }

    // epilogue: C/D layout col = l16-part, row = quad*4 + r
    const float cfreq = -0.10381025296f;  // -log2(10000)/128
    #pragma unroll
    for (int mi = 0; mi < 2; ++mi) {
        #pragma unroll
        for (int ni = 0; ni < 8; ++ni) {
            const int col = ni * 16 + l16;
            #pragma unroll
            for (int r = 0; r < 4; ++r) {
                const int row = row0 + mi * 16 + quad * 4 + r;  // global m (b*T + t)
                const int t   = row & (NT - 1);
                float v = acc[mi][ni][r];
                if (mat < 2) {  // RoPE on Q and K
                    float other = __shfl_xor(v, 1, 64);          // partner col (d^1)
                    float freq  = exp2f(cfreq * (float)(col & ~1));
                    float ang   = (float)t * freq;
                    float sn = sinf(ang), cs = cosf(ang);        // full range reduction
                    v = (col & 1) ? (other * sn + v * cs)        // o1 = x0*sin + x1*cos
                                  : (v * cs - other * sn);       // o0 = x0*cos - x1*sin
                }
                unsigned short bv = f2bf(v);
                if (mat == 0)      qws[(size_t)row * NH + col] = bv;
                else if (mat == 1) kws[(size_t)row * NH + col] = bv;
                else {
                    int b = row >> 11;
                    vtws[(size_t)b * (NH * NT) + (size_t)col * NT + t] = bv;
                }
            }
        }
    }
}

// ---------------------------------------------------------------------------
// Kernel 2: flash attention (causal), 1 wave per 16 Q-rows.
// grid = (128 q-tiles of 16 rows, 8 batches), block = 64.
// QK^T: Q frag in regs (A layout), K read directly (B layout, contiguous).
// Online softmax in C layout; P -> LDS -> A-layout; PV with Vt (contiguous).
// Output written as fp32.
// ---------------------------------------------------------------------------
__global__ __launch_bounds__(64) void attn_k(
    const unsigned short* __restrict__ qws, const unsigned short* __restrict__ kws,
    const unsigned short* __restrict__ vtws, float* __restrict__ out)
{
    __shared__ unsigned short P[16 * 64];
    const int lane = threadIdx.x;
    const int quad = lane >> 4, l16 = lane & 15;
    const int b     = blockIdx.y;
    const int qrow0 = blockIdx.x * 16;
    const unsigned short* Q  = qws  + (size_t)b * NT * NH;
    const unsigned short* K  = kws  + (size_t)b * NT * NH;
    const unsigned short* Vt = vtws + (size_t)b * NH * NT;

    // Q fragments (A layout): lane row = l16, k = ks*32 + quad*8 + j
    s8v qf[4];
    #pragma unroll
    for (int ks = 0; ks < 4; ++ks)
        qf[ks] = *reinterpret_cast<const s8v*>(
            Q + (size_t)(qrow0 + l16) * NH + ks * 32 + quad * 8);

    float m[4], lsum[4];
    f4 o[8];
    #pragma unroll
    for (int r = 0; r < 4; ++r) { m[r] = -INFINITY; lsum[r] = 0.f; }
    #pragma unroll
    for (int dt = 0; dt < 8; ++dt) o[dt] = (f4){0.f, 0.f, 0.f, 0.f};

    const int nkt = (qrow0 >> 6) + 1;        // causal kv-tile count (64-wide tiles)
    const float scale = 0.0883883476f;       // 1/sqrt(128)

    for (int kt = 0; kt < nkt; ++kt) {
        const int kbase = kt * 64;
        const bool domask = (kt == nkt - 1);

        // S = Q K^T  (4 n-subtiles of 16)
        f4 s[4];
        #pragma unroll
        for (int nt = 0; nt < 4; ++nt) {
            f4 a = (f4){0.f, 0.f, 0.f, 0.f};
            #pragma unroll
            for (int ks = 0; ks < 4; ++ks) {
                s8v kf = *reinterpret_cast<const s8v*>(
                    K + (size_t)(kbase + nt * 16 + l16) * NH + ks * 32 + quad * 8);
                a = __builtin_amdgcn_mfma_f32_16x16x32_bf16(qf[ks], kf, a, 0, 0, 0);
            }
            s[nt] = a;
        }

        // online softmax, rows = quad*4 + r, cols spread over 16 lanes x 4 subtiles
        float alpha[4];
        #pragma unroll
        for (int r = 0; r < 4; ++r) {
            const int trow = qrow0 + quad * 4 + r;
            #pragma unroll
            for (int nt = 0; nt < 4; ++nt) {
                float sv = s[nt][r] * scale;
                if (domask && (kbase + nt * 16 + l16 > trow)) sv = -INFINITY;
                s[nt][r] = sv;
            }
            float tm = fmaxf(fmaxf(s[0][r], s[1][r]), fmaxf(s[2][r], s[3][r]));
            #pragma unroll
            for (int off = 1; off < 16; off <<= 1)
                tm = fmaxf(tm, __shfl_xor(tm, off, 64));
            const float mn = fmaxf(m[r], tm);
            alpha[r] = __expf(m[r] - mn);
            m[r] = mn;
            float rs = 0.f;
            #pragma unroll
            for (int nt = 0; nt < 4; ++nt) {
                float p = __expf(s[nt][r] - mn);
                s[nt][r] = p;
                rs += p;
            }
            #pragma unroll
            for (int off = 1; off < 16; off <<= 1)
                rs += __shfl_xor(rs, off, 64);
            lsum[r] = lsum[r] * alpha[r] + rs;
        }

        // P (C layout) -> LDS (row-major 16x64 bf16) for A-layout reads
        #pragma unroll
        for (int nt = 0; nt < 4; ++nt)
            #pragma unroll
            for (int r = 0; r < 4; ++r)
                P[(quad * 4 + r) * 64 + nt * 16 + l16] = f2bf(s[nt][r]);

        // rescale O by alpha before accumulating PV
        #pragma unroll
        for (int dt = 0; dt < 8; ++dt)
            #pragma unroll
            for (int r = 0; r < 4; ++r)
                o[dt][r] *= alpha[r];

        // O += P @ V   (K-dim = 64 -> 2 MFMA k-steps; Vt contiguous in t)
        #pragma unroll
        for (int ks2 = 0; ks2 < 2; ++ks2) {
            s8v pa = *reinterpret_cast<const s8v*>(&P[l16 * 64 + ks2 * 32 + quad * 8]);
            #pragma unroll
            for (int dt = 0; dt < 8; ++dt) {
                s8v vf = *reinterpret_cast<const s8v*>(
                    Vt + (size_t)(dt * 16 + l16) * NT + kbase + ks2 * 32 + quad * 8);
                o[dt] = __builtin_amdgcn_mfma_f32_16x16x32_bf16(pa, vf, o[dt], 0, 0, 0);
            }
        }
    }

    // epilogue: out[b][t][d] = o / l   (fp32 output)
    float* O = out + (size_t)b * NT * NH;
    #pragma unroll
    for (int r = 0; r < 4; ++r) {
        const float rcp = 1.0f / lsum[r];
        const int trow = qrow0 + quad * 4 + r;
        #pragma unroll
        for (int dt = 0; dt < 8; ++dt)
            O[(size_t)trow * NH + dt * 16 + l16] = o[dt][r] * rcp;
    }
}

// ---------------------------------------------------------------------------
extern "C" void kernel_launch(void* const* d_in, const int* in_sizes, int n_in,
                              void* d_out, int out_size, void* d_ws, size_t ws_size,
                              hipStream_t stream) {
    const float* x  = (const float*)d_in[0];
    const float* Wk = (const float*)d_in[1];
    const float* Wq = (const float*)d_in[2];
    const float* Wv = (const float*)d_in[3];
    unsigned short* ws   = (unsigned short*)d_ws;
    unsigned short* wt   = ws;                      // 3 * 262144 elems (Wt: Q,K,V) bf16
    unsigned short* qws  = ws  + 786432;            // 8*2048*128  RoPE'd Q (bf16)
    unsigned short* kws  = qws + 2097152;           // 8*2048*128  RoPE'd K (bf16)
    unsigned short* vtws = kws + 2097152;           // 8*128*2048  V transposed (bf16)
    float* outp = (float*)d_out;

    wtrans_k<<<3072, 256, 0, stream>>>(Wk, Wq, Wv, wt);
    proj_rope<<<dim3(128, 3), 256, 0, stream>>>(x, wt, qws, kws, vtws);
    attn_k<<<dim3(128, 8), 64, 0, stream>>>(qws, kws, vtws, outp);
}

// Round 3
// 370.440 us; speedup vs baseline: 1.3138x; 1.3138x over previous
//
#include <hip/hip_runtime.h>

#define NB 8
#define NT 2048
#define NC 2048
#define NH 128

typedef short s8v __attribute__((ext_vector_type(8)));   // 8 bf16 (4 VGPRs) — MFMA A/B frag
typedef float f4  __attribute__((ext_vector_type(4)));   // 4 fp32 — MFMA C/D frag

static __device__ __forceinline__ unsigned short f2bf(float f) {
    union { float f; unsigned int u; } v; v.f = f;
    unsigned int x = v.u;
    return (unsigned short)((x + 0x7FFFu + ((x >> 16) & 1u)) >> 16);  // RNE
}

// async global->LDS, 16B per lane; LDS dest = wave-uniform base + lane*16 (HW adds lane term)
static __device__ __forceinline__ void gl2lds16(const void* g, void* lds_base) {
    __builtin_amdgcn_global_load_lds(
        (const __attribute__((address_space(1))) unsigned int*)g,
        (__attribute__((address_space(3))) unsigned int*)lds_base, 16, 0, 0);
}

// ---------------------------------------------------------------------------
// Kernel 0: transpose + cast W[k][n] (2048x128 fp32) -> Wt[n][k] (128x2048 bf16)
// ---------------------------------------------------------------------------
__global__ __launch_bounds__(256) void wtrans_k(
    const float* __restrict__ Wk, const float* __restrict__ Wq,
    const float* __restrict__ Wv, unsigned short* __restrict__ wt)
{
    int tid = blockIdx.x * 256 + threadIdx.x;          // 0 .. 786431
    int mat = tid >> 18;
    int r   = tid & 0x3FFFF;
    int n   = r >> 11;
    int k   = r & 2047;
    const float* W = (mat == 0) ? Wq : (mat == 1) ? Wk : Wv;
    wt[tid] = f2bf(W[k * NH + n]);
}

// ---------------------------------------------------------------------------
// Kernel 1: fused projection + RoPE (m97-style).
// grid = (256 row-tiles of 64, 3 matrices), block = 256 = 4 waves (2x2).
// Block tile M=64 x N=128, BK=64. Wt staged via global_load_lds (16 KB/step);
// A-frags read direct from fp32 x, packed to bf16 by truncation (v_perm).
// Wave tile 32x64: 16 MFMA + 8 B ds_read_b128 per BK step.
// ---------------------------------------------------------------------------
__global__ __launch_bounds__(256) void proj_rope(
    const float* __restrict__ x, const unsigned short* __restrict__ wt,
    unsigned short* __restrict__ qws, unsigned short* __restrict__ kws,
    unsigned short* __restrict__ vtws)
{
    __shared__ unsigned short Bs[128 * 64];    // [n][k] 16 KB
    const int mat  = blockIdx.y;               // 0=Q 1=K 2=V
    const int wave = threadIdx.x >> 6;
    const int lane = threadIdx.x & 63;
    const int quad = lane >> 4, l16 = lane & 15;
    const int wm = wave >> 1, wn = wave & 1;   // rows: wm*32, cols: wn*64
    const int M0 = blockIdx.x * 64;
    const unsigned short* wtm = wt + mat * (NH * NC);

    // staging addresses: instr j = wave*4+s covers B rows j*8 + lane/8, k = (lane&7)*8
    const int srow = lane >> 3;                // 0..7
    const int skof = (lane & 7) * 8;           // 0..56

    f4 acc[2][4];
    #pragma unroll
    for (int mi = 0; mi < 2; ++mi)
        #pragma unroll
        for (int ni = 0; ni < 4; ++ni)
            acc[mi][ni] = (f4){0.f, 0.f, 0.f, 0.f};

    for (int kk = 0; kk < NC; kk += 64) {
        // stage Wt tile 128x64 bf16
        #pragma unroll
        for (int s = 0; s < 4; ++s) {
            const int j = wave * 4 + s;
            gl2lds16(wtm + (size_t)(j * 8 + srow) * NC + kk + skof, &Bs[j * 512]);
        }
        __syncthreads();

        #pragma unroll
        for (int ksub = 0; ksub < 2; ++ksub) {
            s8v a[2];
            #pragma unroll
            for (int mi = 0; mi < 2; ++mi) {
                const float* xr = x + (size_t)(M0 + wm * 32 + mi * 16 + l16) * NC
                                    + kk + ksub * 32 + quad * 8;
                union { f4 f; unsigned int u[4]; } L, H;
                L.f = *reinterpret_cast<const f4*>(xr);
                H.f = *reinterpret_cast<const f4*>(xr + 4);
                union { s8v s; unsigned int u[4]; } A;
                A.u[0] = __builtin_amdgcn_perm(L.u[1], L.u[0], 0x07060302u);
                A.u[1] = __builtin_amdgcn_perm(L.u[3], L.u[2], 0x07060302u);
                A.u[2] = __builtin_amdgcn_perm(H.u[1], H.u[0], 0x07060302u);
                A.u[3] = __builtin_amdgcn_perm(H.u[3], H.u[2], 0x07060302u);
                a[mi] = A.s;
            }
            #pragma unroll
            for (int ni = 0; ni < 4; ++ni) {
                s8v b = *reinterpret_cast<const s8v*>(
                    &Bs[(wn * 64 + ni * 16 + l16) * 64 + ksub * 32 + quad * 8]);
                acc[0][ni] = __builtin_amdgcn_mfma_f32_16x16x32_bf16(a[0], b, acc[0][ni], 0, 0, 0);
                acc[1][ni] = __builtin_amdgcn_mfma_f32_16x16x32_bf16(a[1], b, acc[1][ni], 0, 0, 0);
            }
        }
        __syncthreads();
    }

    // epilogue: C/D layout col = l16-part, row = quad*4 + r
    const float cfreq = -0.10381025296f;  // -log2(10000)/128  (unused directly; see exp2f)
    #pragma unroll
    for (int mi = 0; mi < 2; ++mi) {
        #pragma unroll
        for (int ni = 0; ni < 4; ++ni) {
            const int col = wn * 64 + ni * 16 + l16;
            #pragma unroll
            for (int r = 0; r < 4; ++r) {
                const int row = M0 + wm * 32 + mi * 16 + quad * 4 + r;  // b*T + t
                const int t   = row & (NT - 1);
                float v = acc[mi][ni][r];
                if (mat < 2) {  // RoPE on Q and K
                    float other = __shfl_xor(v, 1, 64);
                    float freq  = exp2f(cfreq * (float)(col & ~1));
                    float ang   = (float)t * freq;
                    float sn = sinf(ang), cs = cosf(ang);
                    v = (col & 1) ? (other * sn + v * cs)
                                  : (v * cs - other * sn);
                }
                unsigned short bv = f2bf(v);
                if (mat == 0)      qws[(size_t)row * NH + col] = bv;
                else if (mat == 1) kws[(size_t)row * NH + col] = bv;
                else {
                    int b = row >> 11;
                    vtws[(size_t)b * (NH * NT) + (size_t)col * NT + t] = bv;
                }
            }
        }
    }
}

// ---------------------------------------------------------------------------
// Kernel 2: flash attention (causal), split-KV across 4 waves per block.
// grid = (128 q-tiles of 16 rows, 8 batches), block = 256 (4 waves).
// Wave w handles kv-tiles kt = w, w+4, ... with private online-softmax state;
// partials merged at the end via LDS (global max -> rescale -> sum O, sum l).
// ---------------------------------------------------------------------------
__global__ __launch_bounds__(256) void attn_k(
    const unsigned short* __restrict__ qws, const unsigned short* __restrict__ kws,
    const unsigned short* __restrict__ vtws, float* __restrict__ out)
{
    __shared__ unsigned short P[4][16 * 64];   // per-wave P buffers, 8 KB
    __shared__ float Os[4][16][64];            // 16 KB (half of d per pass)
    __shared__ float Ms[4][16], Ls[4][16], Lt[16];

    const int wave = threadIdx.x >> 6;
    const int lane = threadIdx.x & 63;
    const int quad = lane >> 4, l16 = lane & 15;
    const int b     = blockIdx.y;
    const int qrow0 = blockIdx.x * 16;
    const unsigned short* Q  = qws  + (size_t)b * NT * NH;
    const unsigned short* K  = kws  + (size_t)b * NT * NH;
    const unsigned short* Vt = vtws + (size_t)b * NH * NT;

    // Q fragments (A layout)
    s8v qf[4];
    #pragma unroll
    for (int ks = 0; ks < 4; ++ks)
        qf[ks] = *reinterpret_cast<const s8v*>(
            Q + (size_t)(qrow0 + l16) * NH + ks * 32 + quad * 8);

    float m[4], lsum[4];
    f4 o[8];
    #pragma unroll
    for (int r = 0; r < 4; ++r) { m[r] = -INFINITY; lsum[r] = 0.f; }
    #pragma unroll
    for (int dt = 0; dt < 8; ++dt) o[dt] = (f4){0.f, 0.f, 0.f, 0.f};

    const int nkt = (qrow0 >> 6) + 1;
    const float scale = 0.0883883476f;       // 1/sqrt(128)

    for (int kt = wave; kt < nkt; kt += 4) {
        const int kbase = kt * 64;
        const bool domask = (kt == nkt - 1);

        f4 s[4];
        #pragma unroll
        for (int nt = 0; nt < 4; ++nt) {
            f4 a = (f4){0.f, 0.f, 0.f, 0.f};
            #pragma unroll
            for (int ks = 0; ks < 4; ++ks) {
                s8v kf = *reinterpret_cast<const s8v*>(
                    K + (size_t)(kbase + nt * 16 + l16) * NH + ks * 32 + quad * 8);
                a = __builtin_amdgcn_mfma_f32_16x16x32_bf16(qf[ks], kf, a, 0, 0, 0);
            }
            s[nt] = a;
        }

        float alpha[4];
        #pragma unroll
        for (int r = 0; r < 4; ++r) {
            const int trow = qrow0 + quad * 4 + r;
            #pragma unroll
            for (int nt = 0; nt < 4; ++nt) {
                float sv = s[nt][r] * scale;
                if (domask && (kbase + nt * 16 + l16 > trow)) sv = -INFINITY;
                s[nt][r] = sv;
            }
            float tm = fmaxf(fmaxf(s[0][r], s[1][r]), fmaxf(s[2][r], s[3][r]));
            #pragma unroll
            for (int off = 1; off < 16; off <<= 1)
                tm = fmaxf(tm, __shfl_xor(tm, off, 64));
            const float mn = fmaxf(m[r], tm);
            alpha[r] = __expf(m[r] - mn);
            m[r] = mn;
            float rs = 0.f;
            #pragma unroll
            for (int nt = 0; nt < 4; ++nt) {
                float p = __expf(s[nt][r] - mn);
                s[nt][r] = p;
                rs += p;
            }
            #pragma unroll
            for (int off = 1; off < 16; off <<= 1)
                rs += __shfl_xor(rs, off, 64);
            lsum[r] = lsum[r] * alpha[r] + rs;
        }

        #pragma unroll
        for (int nt = 0; nt < 4; ++nt)
            #pragma unroll
            for (int r = 0; r < 4; ++r)
                P[wave][(quad * 4 + r) * 64 + nt * 16 + l16] = f2bf(s[nt][r]);

        #pragma unroll
        for (int dt = 0; dt < 8; ++dt)
            #pragma unroll
            for (int r = 0; r < 4; ++r)
                o[dt][r] *= alpha[r];

        #pragma unroll
        for (int ks2 = 0; ks2 < 2; ++ks2) {
            s8v pa = *reinterpret_cast<const s8v*>(&P[wave][l16 * 64 + ks2 * 32 + quad * 8]);
            #pragma unroll
            for (int dt = 0; dt < 8; ++dt) {
                s8v vf = *reinterpret_cast<const s8v*>(
                    Vt + (size_t)(dt * 16 + l16) * NT + kbase + ks2 * 32 + quad * 8);
                o[dt] = __builtin_amdgcn_mfma_f32_16x16x32_bf16(pa, vf, o[dt], 0, 0, 0);
            }
        }
    }

    // ---- merge the 4 per-wave partials ----
    if (l16 == 0) {
        #pragma unroll
        for (int r = 0; r < 4; ++r) {
            Ms[wave][quad * 4 + r] = m[r];
            Ls[wave][quad * 4 + r] = lsum[r];
        }
    }
    __syncthreads();

    float sc[4];
    #pragma unroll
    for (int r = 0; r < 4; ++r) {
        const int row = quad * 4 + r;
        float M = fmaxf(fmaxf(Ms[0][row], Ms[1][row]), fmaxf(Ms[2][row], Ms[3][row]));
        sc[r] = __expf(m[r] - M);
        float lt = Ls[0][row] * __expf(Ms[0][row] - M) + Ls[1][row] * __expf(Ms[1][row] - M)
                 + Ls[2][row] * __expf(Ms[2][row] - M) + Ls[3][row] * __expf(Ms[3][row] - M);
        if (wave == 0 && l16 == 0) Lt[row] = lt;
    }
    #pragma unroll
    for (int dt = 0; dt < 8; ++dt)
        #pragma unroll
        for (int r = 0; r < 4; ++r)
            o[dt][r] *= sc[r];

    const int rrow = threadIdx.x >> 4;          // 0..15
    const int rd4  = (threadIdx.x & 15) * 4;    // 0..60
    #pragma unroll
    for (int h = 0; h < 2; ++h) {
        __syncthreads();
        #pragma unroll
        for (int dtl = 0; dtl < 4; ++dtl)
            #pragma unroll
            for (int r = 0; r < 4; ++r)
                Os[wave][quad * 4 + r][dtl * 16 + l16] = o[h * 4 + dtl][r];
        __syncthreads();
        f4 sum = (f4){0.f, 0.f, 0.f, 0.f};
        #pragma unroll
        for (int w = 0; w < 4; ++w)
            sum += *reinterpret_cast<const f4*>(&Os[w][rrow][rd4]);
        const float rl = 1.0f / Lt[rrow];
        f4 res = sum * rl;
        *reinterpret_cast<f4*>(
            &out[((size_t)b * NT + qrow0 + rrow) * NH + h * 64 + rd4]) = res;
    }
}

// ---------------------------------------------------------------------------
extern "C" void kernel_launch(void* const* d_in, const int* in_sizes, int n_in,
                              void* d_out, int out_size, void* d_ws, size_t ws_size,
                              hipStream_t stream) {
    const float* x  = (const float*)d_in[0];
    const float* Wk = (const float*)d_in[1];
    const float* Wq = (const float*)d_in[2];
    const float* Wv = (const float*)d_in[3];
    unsigned short* ws   = (unsigned short*)d_ws;
    unsigned short* wt   = ws;                      // 3 * 262144 (Wt: Q,K,V) bf16
    unsigned short* qws  = ws  + 786432;            // 8*2048*128  RoPE'd Q (bf16)
    unsigned short* kws  = qws + 2097152;           // 8*2048*128  RoPE'd K (bf16)
    unsigned short* vtws = kws + 2097152;           // 8*128*2048  V transposed (bf16)
    float* outp = (float*)d_out;

    wtrans_k<<<3072, 256, 0, stream>>>(Wk, Wq, Wv, wt);
    proj_rope<<<dim3(256, 3), 256, 0, stream>>>(x, wt, qws, kws, vtws);
    attn_k<<<dim3(128, 8), 256, 0, stream>>>(qws, kws, vtws, outp);
}

// Round 4
// 302.593 us; speedup vs baseline: 1.6084x; 1.2242x over previous
//
#include <hip/hip_runtime.h>

#define NB 8
#define NT 2048
#define NC 2048
#define NH 128

typedef short s8v __attribute__((ext_vector_type(8)));   // 8 bf16 (4 VGPRs) — MFMA A/B frag
typedef float f4  __attribute__((ext_vector_type(4)));   // 4 fp32 — MFMA C/D frag

static __device__ __forceinline__ unsigned short f2bf(float f) {
    union { float f; unsigned int u; } v; v.f = f;
    unsigned int x = v.u;
    return (unsigned short)((x + 0x7FFFu + ((x >> 16) & 1u)) >> 16);  // RNE
}

// async global->LDS, 16B/lane; LDS dest = wave-uniform base + lane*16 (HW adds lane term)
static __device__ __forceinline__ void gl2lds16(const void* g, void* lds_base) {
    __builtin_amdgcn_global_load_lds(
        (const __attribute__((address_space(1))) unsigned int*)g,
        (__attribute__((address_space(3))) unsigned int*)lds_base, 16, 0, 0);
}

// ---------------------------------------------------------------------------
// Kernel 0: transpose + cast W[k][n] (2048x128 fp32) -> Wt[n][k] (128x2048 bf16)
// via LDS tile (coalesced read AND write; old version over-fetched 16x).
// grid (32 k-tiles of 64, 3 mats), block 256.
// ---------------------------------------------------------------------------
__global__ __launch_bounds__(256) void wtrans_k(
    const float* __restrict__ Wk, const float* __restrict__ Wq,
    const float* __restrict__ Wv, unsigned short* __restrict__ wt)
{
    __shared__ float Ls[64][129];                       // +1 pad: conflict-free transpose
    const int mat = blockIdx.y;
    const float* W = (mat == 0) ? Wq : (mat == 1) ? Wk : Wv;
    const int k0 = blockIdx.x * 64;
    const int t  = threadIdx.x;

    #pragma unroll
    for (int j = 0; j < 8; ++j) {                       // load 64x128 fp32, coalesced f4
        int flat = j * 1024 + t * 4;
        int k = flat >> 7, n = flat & 127;
        f4 v = *reinterpret_cast<const f4*>(W + (size_t)(k0 + k) * NH + n);
        Ls[k][n] = v[0]; Ls[k][n + 1] = v[1]; Ls[k][n + 2] = v[2]; Ls[k][n + 3] = v[3];
    }
    __syncthreads();

    const int n = t >> 1, half = t & 1;                 // each thread: row n, 32 k's (64B)
    unsigned short tmp[32];
    #pragma unroll
    for (int kk = 0; kk < 32; ++kk) tmp[kk] = f2bf(Ls[half * 32 + kk][n]);
    unsigned short* dst = wt + (size_t)mat * 262144 + (size_t)n * 2048 + k0 + half * 32;
    #pragma unroll
    for (int v = 0; v < 4; ++v)
        *reinterpret_cast<s8v*>(dst + v * 8) = *reinterpret_cast<s8v*>(tmp + v * 8);
}

// ---------------------------------------------------------------------------
// Kernel 1: fused projection + RoPE.
// grid = (256 row-tiles of 64, 3 mats), block 256 (4 waves, 2m x 2n).
// Tile M=64 N=128 BK=64. BOTH operands staged via global_load_lds with XOR
// chunk swizzle (pos = chunk ^ (row & mask)) -> conflict-free b128 reads.
// Xs: 64x64 fp32 (16KB, 16 chunks/row, mask 15). Bs: 128x64 bf16 (16KB,
// 8 chunks/row, mask 7). A packed fp32->bf16 by truncation (v_perm).
// ---------------------------------------------------------------------------
__global__ __launch_bounds__(256) void proj_rope(
    const float* __restrict__ x, const unsigned short* __restrict__ wt,
    unsigned short* __restrict__ qws, unsigned short* __restrict__ kws,
    unsigned short* __restrict__ vtws)
{
    __shared__ char LDS[32768];
    char* XsB = LDS;                // 16 KB
    char* BsB = LDS + 16384;        // 16 KB

    const int mat  = blockIdx.y;
    const int wave = threadIdx.x >> 6;
    const int lane = threadIdx.x & 63;
    const int quad = lane >> 4, l16 = lane & 15;
    const int wm = wave >> 1, wn = wave & 1;
    const int M0 = blockIdx.x * 64;
    const unsigned short* wtm = wt + mat * (NH * NC);

    // staging source addresses (swizzled chunk on the GLOBAL side; LDS dest contiguous)
    const float* xbase[4]; const unsigned short* bbase[4];
    const int bc = (lane & 7) ^ (lane >> 3);            // B chunk, row&7 == lane>>3
    #pragma unroll
    for (int s = 0; s < 4; ++s) {
        const int xrow = wave * 16 + s * 4 + (lane >> 4);
        const int xcol = ((lane & 15) ^ (xrow & 15)) * 4;
        xbase[s] = x + (size_t)(M0 + xrow) * NC + xcol;
        const int brow = wave * 32 + s * 8 + (lane >> 3);
        bbase[s] = wtm + (size_t)brow * NC + bc * 8;
    }

    f4 acc[2][4];
    #pragma unroll
    for (int mi = 0; mi < 2; ++mi)
        #pragma unroll
        for (int ni = 0; ni < 4; ++ni)
            acc[mi][ni] = (f4){0.f, 0.f, 0.f, 0.f};

    for (int kk = 0; kk < NC; kk += 64) {
        #pragma unroll
        for (int s = 0; s < 4; ++s)
            gl2lds16(xbase[s] + kk, XsB + (wave * 4 + s) * 1024);
        #pragma unroll
        for (int s = 0; s < 4; ++s)
            gl2lds16(bbase[s] + kk, BsB + (wave * 4 + s) * 1024);
        __syncthreads();

        #pragma unroll
        for (int ksub = 0; ksub < 2; ++ksub) {
            s8v a[2];
            #pragma unroll
            for (int mi = 0; mi < 2; ++mi) {
                const int rb = (wm * 32 + mi * 16 + l16) * 256;   // row*256B, row&15==l16
                const int p0 = (ksub * 8 + quad * 2) ^ l16;       // even chunk
                union { f4 f; unsigned int u[4]; } L, H;
                L.f = *reinterpret_cast<const f4*>(XsB + rb + p0 * 16);
                H.f = *reinterpret_cast<const f4*>(XsB + rb + (p0 ^ 1) * 16);
                union { s8v s; unsigned int u[4]; } A;
                A.u[0] = __builtin_amdgcn_perm(L.u[1], L.u[0], 0x07060302u);
                A.u[1] = __builtin_amdgcn_perm(L.u[3], L.u[2], 0x07060302u);
                A.u[2] = __builtin_amdgcn_perm(H.u[1], H.u[0], 0x07060302u);
                A.u[3] = __builtin_amdgcn_perm(H.u[3], H.u[2], 0x07060302u);
                a[mi] = A.s;
            }
            #pragma unroll
            for (int ni = 0; ni < 4; ++ni) {
                const int row2 = wn * 64 + ni * 16 + l16;         // row&7 == l16&7
                const int pb = (ksub * 4 + quad) ^ (l16 & 7);
                s8v b = *reinterpret_cast<const s8v*>(BsB + row2 * 128 + pb * 16);
                acc[0][ni] = __builtin_amdgcn_mfma_f32_16x16x32_bf16(a[0], b, acc[0][ni], 0, 0, 0);
                acc[1][ni] = __builtin_amdgcn_mfma_f32_16x16x32_bf16(a[1], b, acc[1][ni], 0, 0, 0);
            }
        }
        __syncthreads();
    }

    // epilogue: C/D layout col = l16-part, row = quad*4 + r
    const float cfreq = -0.10381025296f;  // -log2(10000)/128
    #pragma unroll
    for (int mi = 0; mi < 2; ++mi) {
        #pragma unroll
        for (int ni = 0; ni < 4; ++ni) {
            const int col = wn * 64 + ni * 16 + l16;
            #pragma unroll
            for (int r = 0; r < 4; ++r) {
                const int row = M0 + wm * 32 + mi * 16 + quad * 4 + r;  // b*T + t
                const int t   = row & (NT - 1);
                float v = acc[mi][ni][r];
                if (mat < 2) {
                    float other = __shfl_xor(v, 1, 64);
                    float freq  = exp2f(cfreq * (float)(col & ~1));
                    float ang   = (float)t * freq;
                    float sn = sinf(ang), cs = cosf(ang);
                    v = (col & 1) ? (other * sn + v * cs)
                                  : (v * cs - other * sn);
                }
                unsigned short bv = f2bf(v);
                if (mat == 0)      qws[(size_t)row * NH + col] = bv;
                else if (mat == 1) kws[(size_t)row * NH + col] = bv;
                else {
                    int b = row >> 11;
                    vtws[(size_t)b * (NH * NT) + (size_t)col * NT + t] = bv;
                }
            }
        }
    }
}

// ---------------------------------------------------------------------------
// Kernel 2: flash attention (causal). 32 q-rows per wave (2 m-frags),
// split-KV stride 4 across the block's 4 waves, private online-softmax state,
// LDS merge at the end. grid = (64 q-tiles of 32, 8 batches), block 256.
// P buffer XOR-swizzled (8-short chunks) -> conflict-free b128 A-frag reads.
// ---------------------------------------------------------------------------
__global__ __launch_bounds__(256, 2) void attn_k(
    const unsigned short* __restrict__ qws, const unsigned short* __restrict__ kws,
    const unsigned short* __restrict__ vtws, float* __restrict__ out)
{
    __shared__ unsigned short P[4][32 * 64];   // 16 KB, per-wave, swizzled
    __shared__ float Os[4][32][64];            // 32 KB (one half of d per pass)
    __shared__ float Ms[4][32], Ls[4][32], Lt[32];

    const int wave = threadIdx.x >> 6;
    const int lane = threadIdx.x & 63;
    const int quad = lane >> 4, l16 = lane & 15;
    const int b     = blockIdx.y;
    const int qrow0 = blockIdx.x * 32;
    const unsigned short* Q  = qws  + (size_t)b * NT * NH;
    const unsigned short* K  = kws  + (size_t)b * NT * NH;
    const unsigned short* Vt = vtws + (size_t)b * NH * NT;

    s8v qf[2][4];
    #pragma unroll
    for (int mi = 0; mi < 2; ++mi)
        #pragma unroll
        for (int ks = 0; ks < 4; ++ks)
            qf[mi][ks] = *reinterpret_cast<const s8v*>(
                Q + (size_t)(qrow0 + mi * 16 + l16) * NH + ks * 32 + quad * 8);

    float m[2][4], ls[2][4];
    f4 o[2][8];
    #pragma unroll
    for (int mi = 0; mi < 2; ++mi) {
        #pragma unroll
        for (int r = 0; r < 4; ++r) { m[mi][r] = -INFINITY; ls[mi][r] = 0.f; }
        #pragma unroll
        for (int dt = 0; dt < 8; ++dt) o[mi][dt] = (f4){0.f, 0.f, 0.f, 0.f};
    }

    const int nkt = (qrow0 >> 6) + 1;        // works for qrow0 = 0/32 mod 64
    const float scale = 0.0883883476f;       // 1/sqrt(128)

    for (int kt = wave; kt < nkt; kt += 4) {
        const int kbase = kt * 64;
        const bool domask = (kt == nkt - 1);

        // S = Q K^T
        f4 s[2][4];
        #pragma unroll
        for (int nt = 0; nt < 4; ++nt) {
            f4 a0 = (f4){0.f, 0.f, 0.f, 0.f}, a1 = a0;
            #pragma unroll
            for (int ks = 0; ks < 4; ++ks) {
                s8v kf = *reinterpret_cast<const s8v*>(
                    K + (size_t)(kbase + nt * 16 + l16) * NH + ks * 32 + quad * 8);
                a0 = __builtin_amdgcn_mfma_f32_16x16x32_bf16(qf[0][ks], kf, a0, 0, 0, 0);
                a1 = __builtin_amdgcn_mfma_f32_16x16x32_bf16(qf[1][ks], kf, a1, 0, 0, 0);
            }
            s[0][nt] = a0; s[1][nt] = a1;
        }

        // online softmax; lsum kept per-lane (reduced once after the loop)
        #pragma unroll
        for (int mi = 0; mi < 2; ++mi) {
            #pragma unroll
            for (int r = 0; r < 4; ++r) {
                const int trow = qrow0 + mi * 16 + quad * 4 + r;
                #pragma unroll
                for (int nt = 0; nt < 4; ++nt) {
                    float sv = s[mi][nt][r] * scale;
                    if (domask && (kbase + nt * 16 + l16 > trow)) sv = -INFINITY;
                    s[mi][nt][r] = sv;
                }
                float tm = fmaxf(fmaxf(s[mi][0][r], s[mi][1][r]),
                                 fmaxf(s[mi][2][r], s[mi][3][r]));
                #pragma unroll
                for (int off = 1; off < 16; off <<= 1)
                    tm = fmaxf(tm, __shfl_xor(tm, off, 64));
                const float mn = fmaxf(m[mi][r], tm);
                const float alpha = __expf(m[mi][r] - mn);
                m[mi][r] = mn;
                float rs = 0.f;
                #pragma unroll
                for (int nt = 0; nt < 4; ++nt) {
                    float p = __expf(s[mi][nt][r] - mn);
                    s[mi][nt][r] = p;
                    rs += p;
                }
                ls[mi][r] = ls[mi][r] * alpha + rs;
                #pragma unroll
                for (int dt = 0; dt < 8; ++dt) o[mi][dt][r] *= alpha;
            }
        }

        // P (C layout) -> LDS, XOR-swizzled: pos = chunk ^ (row&7), chunk=8 shorts
        #pragma unroll
        for (int mi = 0; mi < 2; ++mi)
            #pragma unroll
            for (int nt = 0; nt < 4; ++nt)
                #pragma unroll
                for (int r = 0; r < 4; ++r) {
                    const int prow = mi * 16 + quad * 4 + r;
                    const int swz  = ((nt * 2 + (l16 >> 3)) ^ (prow & 7)) * 8 + (l16 & 7);
                    P[wave][prow * 64 + swz] = f2bf(s[mi][nt][r]);
                }

        // O += P @ V
        #pragma unroll
        for (int ks2 = 0; ks2 < 2; ++ks2) {
            s8v pa[2];
            #pragma unroll
            for (int mi = 0; mi < 2; ++mi) {
                const int prow = mi * 16 + l16;                  // prow&7 == l16&7
                const int pp = ((ks2 * 4 + quad) ^ (l16 & 7));
                pa[mi] = *reinterpret_cast<const s8v*>(&P[wave][prow * 64 + pp * 8]);
            }
            #pragma unroll
            for (int dt = 0; dt < 8; ++dt) {
                s8v vf = *reinterpret_cast<const s8v*>(
                    Vt + (size_t)(dt * 16 + l16) * NT + kbase + ks2 * 32 + quad * 8);
                o[0][dt] = __builtin_amdgcn_mfma_f32_16x16x32_bf16(pa[0], vf, o[0][dt], 0, 0, 0);
                o[1][dt] = __builtin_amdgcn_mfma_f32_16x16x32_bf16(pa[1], vf, o[1][dt], 0, 0, 0);
            }
        }
    }

    // reduce per-lane lsum across the 16-lane row group
    #pragma unroll
    for (int mi = 0; mi < 2; ++mi)
        #pragma unroll
        for (int r = 0; r < 4; ++r) {
            float v = ls[mi][r];
            #pragma unroll
            for (int off = 1; off < 16; off <<= 1) v += __shfl_xor(v, off, 64);
            ls[mi][r] = v;
        }

    // ---- merge the 4 per-wave partials ----
    if (l16 == 0) {
        #pragma unroll
        for (int mi = 0; mi < 2; ++mi)
            #pragma unroll
            for (int r = 0; r < 4; ++r) {
                Ms[wave][mi * 16 + quad * 4 + r] = m[mi][r];
                Ls[wave][mi * 16 + quad * 4 + r] = ls[mi][r];
            }
    }
    __syncthreads();

    #pragma unroll
    for (int mi = 0; mi < 2; ++mi)
        #pragma unroll
        for (int r = 0; r < 4; ++r) {
            const int row = mi * 16 + quad * 4 + r;
            float M = fmaxf(fmaxf(Ms[0][row], Ms[1][row]), fmaxf(Ms[2][row], Ms[3][row]));
            float sc = __expf(m[mi][r] - M);
            float lt = Ls[0][row] * __expf(Ms[0][row] - M) + Ls[1][row] * __expf(Ms[1][row] - M)
                     + Ls[2][row] * __expf(Ms[2][row] - M) + Ls[3][row] * __expf(Ms[3][row] - M);
            if (wave == 0 && l16 == 0) Lt[row] = lt;
            #pragma unroll
            for (int dt = 0; dt < 8; ++dt) o[mi][dt][r] *= sc;
        }

    const int rrow = threadIdx.x >> 3;          // 0..31
    const int cx   = (threadIdx.x & 7) * 8;     // 0..56
    #pragma unroll
    for (int h = 0; h < 2; ++h) {
        __syncthreads();
        #pragma unroll
        for (int mi = 0; mi < 2; ++mi)
            #pragma unroll
            for (int dtl = 0; dtl < 4; ++dtl)
                #pragma unroll
                for (int r = 0; r < 4; ++r)
                    Os[wave][mi * 16 + quad * 4 + r][dtl * 16 + l16] = o[mi][h * 4 + dtl][r];
        __syncthreads();
        f4 s0 = (f4){0.f, 0.f, 0.f, 0.f}, s1 = s0;
        #pragma unroll
        for (int w = 0; w < 4; ++w) {
            s0 += *reinterpret_cast<const f4*>(&Os[w][rrow][cx]);
            s1 += *reinterpret_cast<const f4*>(&Os[w][rrow][cx + 4]);
        }
        const float rl = 1.0f / Lt[rrow];
        float* dst = &out[((size_t)b * NT + qrow0 + rrow) * NH + h * 64 + cx];
        *reinterpret_cast<f4*>(dst)     = s0 * rl;
        *reinterpret_cast<f4*>(dst + 4) = s1 * rl;
    }
}

// ---------------------------------------------------------------------------
extern "C" void kernel_launch(void* const* d_in, const int* in_sizes, int n_in,
                              void* d_out, int out_size, void* d_ws, size_t ws_size,
                              hipStream_t stream) {
    const float* x  = (const float*)d_in[0];
    const float* Wk = (const float*)d_in[1];
    const float* Wq = (const float*)d_in[2];
    const float* Wv = (const float*)d_in[3];
    unsigned short* ws   = (unsigned short*)d_ws;
    unsigned short* wt   = ws;                      // 3 * 262144 (Wt: Q,K,V) bf16
    unsigned short* qws  = ws  + 786432;            // 8*2048*128  RoPE'd Q (bf16)
    unsigned short* kws  = qws + 2097152;           // 8*2048*128  RoPE'd K (bf16)
    unsigned short* vtws = kws + 2097152;           // 8*128*2048  V transposed (bf16)
    float* outp = (float*)d_out;

    wtrans_k<<<dim3(32, 3), 256, 0, stream>>>(Wk, Wq, Wv, wt);
    proj_rope<<<dim3(256, 3), 256, 0, stream>>>(x, wt, qws, kws, vtws);
    attn_k<<<dim3(64, 8), 256, 0, stream>>>(qws, kws, vtws, outp);
}